// Round 4
// baseline (401.191 us; speedup 1.0000x reference)
//
#include <hip/hip_runtime.h>
#include <cstdint>
#include <cstddef>

#define NN 250000   // nodes
#define FF 256      // channels
#define GG 4096     // graphs
#define TT 6        // processing steps

typedef _Float16 half8_t __attribute__((ext_vector_type(8)));
typedef _Float16 half4_t __attribute__((ext_vector_type(4)));
typedef float f32x4 __attribute__((ext_vector_type(4)));

// ---------------- one-time prep ----------------
// W_comb[j][k] = Wih[j][k] + (k<256 ? Whh[j][k] : 0), cast f16. bias = bih+bhh.
__global__ __launch_bounds__(256) void prep_w_kernel(
    const float* __restrict__ Wih, const float* __restrict__ Whh,
    const float* __restrict__ bih, const float* __restrict__ bhh,
    _Float16* __restrict__ w16, float* __restrict__ bias) {
  int idx = blockIdx.x * 256 + threadIdx.x;
  if (idx < 4 * FF) bias[idx] = bih[idx] + bhh[idx];
  if (idx >= 4 * FF * 2 * FF) return;
  int j = idx >> 9;
  int k = idx & 511;
  float v = Wih[(size_t)j * (2 * FF) + k];
  if (k < FF) v += Whh[(size_t)j * FF + k];
  w16[idx] = (_Float16)v;
}

// starts[g] = lower_bound(batch, g); starts[GG] = NN  (batch sorted)
__global__ __launch_bounds__(256) void find_starts_kernel(
    const int* __restrict__ batch, int* __restrict__ starts) {
  int g = blockIdx.x * 256 + threadIdx.x;
  if (g > GG) return;
  if (g == GG) { starts[GG] = NN; return; }
  int lo = 0, hi = NN;
  while (lo < hi) {
    int mid = (lo + hi) >> 1;
    if (batch[mid] < g) lo = mid + 1; else hi = mid;
  }
  starts[g] = lo;
}

// ---------------- fused gates-GEMM + LSTM pointwise ----------------
// Block: 32 graphs x 32 f-channels, W-cols {f, f+256, f+512, f+768} so each
// thread holds all 4 gates of its (g,f). Grid (128, 8) = 1024 blocks
// (4 blocks/CU = 16 waves/CU for L2-latency hiding; R3's 512 had only 8).
__global__ __launch_bounds__(256) void gemm_lstm_kernel(
    const _Float16* __restrict__ q16in, const _Float16* __restrict__ w16,
    const float* __restrict__ bias, float* __restrict__ c,
    float* __restrict__ qstar, _Float16* __restrict__ q16out) {
  int lane = threadIdx.x & 63;
  int w    = threadIdx.x >> 6;
  int wm = w >> 1, wn = w & 1;
  int g0 = blockIdx.x * 32 + wm * 16;   // graph rows (A rows)
  int f0 = blockIdx.y * 32 + wn * 16;   // f-channel (per-gate col offset)
  int lr = lane & 15, kq = lane >> 4;

  f32x4 acc[4];
#pragma unroll
  for (int gt = 0; gt < 4; ++gt) acc[gt] = (f32x4){0.f, 0.f, 0.f, 0.f};

#pragma unroll
  for (int k0 = 0; k0 < 512; k0 += 32) {
    int kk = k0 + kq * 8;
    half8_t a = *(const half8_t*)(q16in + (size_t)(g0 + lr) * 512 + kk);
    half8_t b[4];
#pragma unroll
    for (int gt = 0; gt < 4; ++gt)
      b[gt] = *(const half8_t*)(w16 + (size_t)(gt * 256 + f0 + lr) * 512 + kk);
#pragma unroll
    for (int gt = 0; gt < 4; ++gt)
      acc[gt] = __builtin_amdgcn_mfma_f32_16x16x32_f16(a, b[gt], acc[gt], 0, 0, 0);
  }

  // epilogue: LSTM pointwise fully in-register
  int f = f0 + lr;
#pragma unroll
  for (int r = 0; r < 4; ++r) {
    int g = g0 + kq * 4 + r;
    float ig = acc[0][r] + bias[f];
    float fg = acc[1][r] + bias[f + 256];
    float gv = acc[2][r] + bias[f + 512];
    float og = acc[3][r] + bias[f + 768];
    float si = 1.f / (1.f + __expf(-ig));
    float sf = 1.f / (1.f + __expf(-fg));
    float so = 1.f / (1.f + __expf(-og));
    size_t ci = (size_t)g * FF + f;
    float cv = sf * c[ci] + si * tanhf(gv);
    float hv = so * tanhf(cv);
    c[ci] = cv;
    qstar[(size_t)g * 512 + f] = hv;
    q16out[(size_t)g * 512 + f] = (_Float16)hv;
  }
}

// ---------------- single-pass attention (online softmax) ----------------
// One block per graph; 16 virtual waves of 16 lanes, each vw owns one node
// per iteration (16 channels/lane, split c0=[l*8,+8) and c1=[128+l*8,+8) so
// every half8 load is 256 B contiguous per quarter). Reduction = 4 shfl_xor
// steps within 16 lanes. Independent online-softmax state per vw, merged in
// LDS at the end.
// T0: t==0 — h = f(bias) in-kernel (GEMM of zeros). XMODE: 0 = x32,
// 1 = x32 non-temporal + write x16 mirror, 2 = read x16.
template <bool T0, int XMODE>
__global__ __launch_bounds__(256) void attn_kernel(
    const float* __restrict__ x32, const _Float16* __restrict__ x16r,
    _Float16* __restrict__ x16w, const int* __restrict__ starts,
    const float* __restrict__ bias, float* __restrict__ c,
    float* __restrict__ qstar, _Float16* __restrict__ q16out) {
  int g = blockIdx.x;
  int tid = threadIdx.x;
  int vw = tid >> 4;
  int l  = tid & 15;

  __shared__ __align__(16) float h_sh[FF];
  __shared__ __align__(16) float rw[16][FF];
  __shared__ float mw[16], sw[16];

  if (T0) {
    float ig = bias[tid], gv = bias[tid + 512], og = bias[tid + 768];
    float si = 1.f / (1.f + __expf(-ig));
    float so = 1.f / (1.f + __expf(-og));
    float cv = si * tanhf(gv);
    float hv = so * tanhf(cv);
    c[(size_t)g * FF + tid] = cv;
    qstar[(size_t)g * 512 + tid] = hv;
    q16out[(size_t)g * 512 + tid] = (_Float16)hv;
    h_sh[tid] = hv;
  } else {
    h_sh[tid] = qstar[(size_t)g * 512 + tid];
  }
  __syncthreads();

  float q0[8], q1[8];
#pragma unroll
  for (int j = 0; j < 8; ++j) {
    q0[j] = h_sh[l * 8 + j];
    q1[j] = h_sh[128 + l * 8 + j];
  }

  int s0 = starts[g];
  int cnt = starts[g + 1] - s0;

  float m = -INFINITY, ssum = 0.f;
  float r0[8], r1[8];
#pragma unroll
  for (int j = 0; j < 8; ++j) { r0[j] = 0.f; r1[j] = 0.f; }

  for (int i = vw; i < cnt; i += 16) {
    const size_t base = (size_t)(s0 + i) * FF;
    float xv0[8], xv1[8];
    if (XMODE == 2) {
      half8_t ha = *(const half8_t*)(x16r + base + l * 8);
      half8_t hb = *(const half8_t*)(x16r + base + 128 + l * 8);
#pragma unroll
      for (int j = 0; j < 8; ++j) { xv0[j] = (float)ha[j]; xv1[j] = (float)hb[j]; }
    } else {
      const float* xp = x32 + base;
      f32x4 a0, a1, b0, b1;
      if (XMODE == 1) {
        a0 = __builtin_nontemporal_load((const f32x4*)(xp + l * 8));
        a1 = __builtin_nontemporal_load((const f32x4*)(xp + l * 8 + 4));
        b0 = __builtin_nontemporal_load((const f32x4*)(xp + 128 + l * 8));
        b1 = __builtin_nontemporal_load((const f32x4*)(xp + 128 + l * 8 + 4));
      } else {
        a0 = *(const f32x4*)(xp + l * 8);
        a1 = *(const f32x4*)(xp + l * 8 + 4);
        b0 = *(const f32x4*)(xp + 128 + l * 8);
        b1 = *(const f32x4*)(xp + 128 + l * 8 + 4);
      }
#pragma unroll
      for (int j = 0; j < 4; ++j) {
        xv0[j] = a0[j]; xv0[4 + j] = a1[j];
        xv1[j] = b0[j]; xv1[4 + j] = b1[j];
      }
      if (XMODE == 1) {
        half8_t ha, hb;
#pragma unroll
        for (int j = 0; j < 8; ++j) {
          ha[j] = (_Float16)xv0[j]; hb[j] = (_Float16)xv1[j];
        }
        *(half8_t*)(x16w + base + l * 8) = ha;
        *(half8_t*)(x16w + base + 128 + l * 8) = hb;
      }
    }
    float d = 0.f;
#pragma unroll
    for (int j = 0; j < 8; ++j) d += xv0[j] * q0[j] + xv1[j] * q1[j];
#pragma unroll
    for (int off = 1; off < 16; off <<= 1) d += __shfl_xor(d, off);
    if (d > m) {  // uniform within the 16-lane quarter
      float sc = __expf(m - d);  // first iter: exp(-inf)=0
      ssum *= sc;
#pragma unroll
      for (int j = 0; j < 8; ++j) { r0[j] *= sc; r1[j] *= sc; }
      m = d;
    }
    float p = __expf(d - m);
    ssum += p;
#pragma unroll
    for (int j = 0; j < 8; ++j) { r0[j] += p * xv0[j]; r1[j] += p * xv1[j]; }
  }

  if (l == 0) { mw[vw] = m; sw[vw] = ssum; }
#pragma unroll
  for (int j = 0; j < 8; ++j) {
    rw[vw][l * 8 + j] = r0[j];
    rw[vw][128 + l * 8 + j] = r1[j];
  }
  __syncthreads();

  float M = mw[0];
#pragma unroll
  for (int v = 1; v < 16; ++v) M = fmaxf(M, mw[v]);
  float denom = 0.f, rsum = 0.f;
#pragma unroll
  for (int v = 0; v < 16; ++v) {
    float e = (mw[v] == -INFINITY) ? 0.f : __expf(mw[v] - M);
    denom += sw[v] * e;
    rsum += rw[v][tid] * e;
  }
  float r = rsum / (denom + 1e-16f);
  if (cnt == 0) r = 0.f;
  qstar[(size_t)g * 512 + FF + tid] = r;
  q16out[(size_t)g * 512 + FF + tid] = (_Float16)r;
}

// ---------------- launcher ----------------
extern "C" void kernel_launch(void* const* d_in, const int* in_sizes, int n_in,
                              void* d_out, int out_size, void* d_ws, size_t ws_size,
                              hipStream_t stream) {
  const float* x   = (const float*)d_in[0];
  const int* batch = (const int*)d_in[1];
  // d_in[2] = size (4096), hard-coded
  const float* Wih = (const float*)d_in[3];
  const float* Whh = (const float*)d_in[4];
  const float* bih = (const float*)d_in[5];
  const float* bhh = (const float*)d_in[6];
  float* qstar = (float*)d_out;  // [GG, 512]; final value IS the output

  uint8_t* p = (uint8_t*)d_ws;
  auto alloc = [&](size_t bytes) {
    uint8_t* q = p;
    p += (bytes + 255) & ~(size_t)255;
    return q;
  };
  float* c_st    = (float*)alloc((size_t)GG * FF * 4);            // 4 MB
  _Float16* q16a = (_Float16*)alloc((size_t)GG * 2 * FF * 2);     // 4 MB
  _Float16* q16b = (_Float16*)alloc((size_t)GG * 2 * FF * 2);     // 4 MB
  _Float16* w16  = (_Float16*)alloc((size_t)4 * FF * 2 * FF * 2); // 1 MB
  float* bias    = (float*)alloc((size_t)4 * FF * 4);
  int* starts    = (int*)alloc((size_t)(GG + 1) * 4);
  _Float16* x16  = (_Float16*)alloc((size_t)NN * FF * 2);         // 128 MB
  bool use16 = ((size_t)(p - (uint8_t*)d_ws) <= ws_size);

  prep_w_kernel<<<(4 * FF * 2 * FF + 255) / 256, 256, 0, stream>>>(
      Wih, Whh, bih, bhh, w16, bias);
  find_starts_kernel<<<(GG + 1 + 255) / 256, 256, 0, stream>>>(batch, starts);

  if (use16) {
    // t = 0: bias-only LSTM, read x32 (non-temporal), write x16 mirror
    attn_kernel<true, 1><<<GG, 256, 0, stream>>>(
        x, nullptr, x16, starts, bias, c_st, qstar, q16a);
    for (int t = 1; t < TT; ++t) {
      _Float16* qin  = (t & 1) ? q16a : q16b;
      _Float16* qout = (t & 1) ? q16b : q16a;
      gemm_lstm_kernel<<<dim3(128, 8), 256, 0, stream>>>(
          qin, w16, bias, c_st, qstar, qout);
      attn_kernel<false, 2><<<GG, 256, 0, stream>>>(
          nullptr, x16, nullptr, starts, bias, c_st, qstar, qout);
    }
  } else {  // workspace too small for x16 mirror: f32 path
    attn_kernel<true, 0><<<GG, 256, 0, stream>>>(
        x, nullptr, nullptr, starts, bias, c_st, qstar, q16a);
    for (int t = 1; t < TT; ++t) {
      _Float16* qin  = (t & 1) ? q16a : q16b;
      _Float16* qout = (t & 1) ? q16b : q16a;
      gemm_lstm_kernel<<<dim3(128, 8), 256, 0, stream>>>(
          qin, w16, bias, c_st, qstar, qout);
      attn_kernel<false, 0><<<GG, 256, 0, stream>>>(
          x, nullptr, nullptr, starts, bias, c_st, qstar, qout);
    }
  }
}